// Round 1
// 378.258 us; speedup vs baseline: 1.0920x; 1.0920x over previous
//
#include <hip/hip_runtime.h>
#include <hip/hip_bf16.h>

// N=1048576, D_IN=48, D_ATT=8
// Algebra: scores = Wq G Wk^T/sqrt(8), G = x^T x  [48x48]
//          v = x @ Wv^T  [N x 8]  (materialized bf16 in pass 1)
//          out = v @ W2, W2 = softmax(scores) Wo^T  [8x48]
// Pass 1 (k_gram_v): G via bf16 MFMA + fused v=x@Wv^T via bf16 MFMA (row-major
//   LDS copy). 1024 blocks (4/CU) for latency hiding; 32-row wave-private tiles.
// Pass 2 (k_combine): epilogue -> Mt2[48 cols][8 k] bf16 B-fragment table.
// Pass 3 (k_out_v): out = v @ W2 via MFMA (K=8 zero-padded to 32). LDS-free,
//   2048 blocks, ~32 waves/CU. Reads 16.8 MB instead of 201 MB.

#define DI 48

typedef __attribute__((ext_vector_type(8))) short short8;   // 8 bf16 = 4 VGPRs
typedef __attribute__((ext_vector_type(4))) float f32x4;

__device__ inline unsigned int pack_bf16(float lo, float hi) {
  __hip_bfloat162 h = __float22bfloat162_rn(make_float2(lo, hi));
  return *reinterpret_cast<unsigned int*>(&h);
}

constexpr int GB1 = 1024;  // k_gram_v blocks (exactly 4/CU)
constexpr int GB2 = 2048;  // k_out_v blocks  (8/CU)
constexpr int SDT = 20;    // dwords per transposed bf16 column (16 row-pairs + pad 4)
constexpr int SDR = 28;    // dwords per row-major bf16 row (24 + pad 4, 16B-aligned)
constexpr int WDW = 48 * SDT + 32 * SDR;  // 960 + 896 = 1856 dwords per wave

// ---------------- K1: G = x^T x  +  v = x @ Wv^T ----------------
// 1024 blocks x 256 thr. Wave owns 256 contiguous rows = 8 tiles of 32.
// Per tile: stage 32x48 fp32 -> BOTH transposed bf16 (Gram frags, K=rows) and
// row-major bf16 (v A-frags, K=cols). 9 Gram MFMA (K=32 exact) + 4 v MFMA.
__global__ __launch_bounds__(256) void k_gram_v(const float* __restrict__ x,
                                                const float* __restrict__ Wv,
                                                float* __restrict__ G,
                                                __hip_bfloat16* __restrict__ v,
                                                int N) {
  __shared__ unsigned int sh[4 * WDW];  // 29696 B; reused for reduction
  const int tid = threadIdx.x;
  const int wave = tid >> 6, lane = tid & 63;
  unsigned int* xt = &sh[wave * WDW];       // transposed: [48 cols][SDT]
  unsigned int* xr = xt + 48 * SDT;         // row-major:  [32 rows][SDR]
  const int quad = lane >> 4, m = lane & 15;

  // Wv B-fragments for v = x@Wv^T: B[k=c][col=p] = Wv[p][c].
  // wv0: c = 8*quad + j (cols 0..31); wv1: c = 32+8*quad+j (cols 32..47, quad<2).
  short8 wv0 = {}, wv1 = {};
  if (m < 8) {
    const float* wrow = Wv + m * DI + 8 * quad;
    float4 c0 = *(const float4*)(wrow);
    float4 c1 = *(const float4*)(wrow + 4);
    unsigned int u0[4] = { pack_bf16(c0.x, c0.y), pack_bf16(c0.z, c0.w),
                           pack_bf16(c1.x, c1.y), pack_bf16(c1.z, c1.w) };
    wv0 = *(const short8*)u0;
    if (quad < 2) {
      float4 d0 = *(const float4*)(wrow + 32);
      float4 d1 = *(const float4*)(wrow + 36);
      unsigned int u1[4] = { pack_bf16(d0.x, d0.y), pack_bf16(d0.z, d0.w),
                             pack_bf16(d1.x, d1.y), pack_bf16(d1.z, d1.w) };
      wv1 = *(const short8*)u1;
    }
  }

  f32x4 acc[3][3] = {};

  const int rows_per_block = N / GB1;            // 1024
  const int rows_per_wave = rows_per_block >> 2; // 256
  const int ntiles = rows_per_wave >> 5;         // 8
  const long long base0 = (long long)blockIdx.x * rows_per_block + wave * rows_per_wave;

  for (int tile = 0; tile < ntiles; ++tile) {
    const long long rowt = base0 + (long long)tile * 32;
    const float* src = x + rowt * DI;
    // ---- stage: 192 tasks (16 row-pairs x 12 col-groups), 3 per lane ----
    float4 va[3], vb[3];
    int rp_[3], cg_[3];
#pragma unroll
    for (int s = 0; s < 3; ++s) {
      int task = lane + 64 * s;
      int rp = task / 12, cg = task % 12;
      rp_[s] = rp; cg_[s] = cg;
      const float4* p = (const float4*)(src + (2 * rp) * DI) + cg;
      va[s] = p[0];
      vb[s] = *(const float4*)((const float*)p + DI);
    }
#pragma unroll
    for (int s = 0; s < 3; ++s) {
      int rp = rp_[s], cg = cg_[s];
      int c0 = 4 * cg;
      // transposed (rows paired in dwords)
      xt[(c0 + 0) * SDT + rp] = pack_bf16(va[s].x, vb[s].x);
      xt[(c0 + 1) * SDT + rp] = pack_bf16(va[s].y, vb[s].y);
      xt[(c0 + 2) * SDT + rp] = pack_bf16(va[s].z, vb[s].z);
      xt[(c0 + 3) * SDT + rp] = pack_bf16(va[s].w, vb[s].w);
      // row-major
      unsigned int ra[2] = { pack_bf16(va[s].x, va[s].y), pack_bf16(va[s].z, va[s].w) };
      unsigned int rb[2] = { pack_bf16(vb[s].x, vb[s].y), pack_bf16(vb[s].z, vb[s].w) };
      *(uint2*)&xr[(2 * rp) * SDR + 2 * cg]     = *(const uint2*)ra;
      *(uint2*)&xr[(2 * rp + 1) * SDR + 2 * cg] = *(const uint2*)rb;
    }
    asm volatile("s_waitcnt lgkmcnt(0)" ::: "memory");
    // ---- Gram: single K=32 step (contraction over the 32 tile rows) ----
    short8 f[3];
#pragma unroll
    for (int t = 0; t < 3; ++t)
      f[t] = *(const short8*)&xt[(16 * t + m) * SDT + quad * 4];
#pragma unroll
    for (int i = 0; i < 3; ++i)
#pragma unroll
      for (int j = 0; j < 3; ++j)
        acc[i][j] = __builtin_amdgcn_mfma_f32_16x16x32_bf16(f[i], f[j], acc[i][j], 0, 0, 0);
    // ---- v = x @ Wv^T for these 32 rows (2 groups of 16) ----
#pragma unroll
    for (int g = 0; g < 2; ++g) {
      short8 a0 = *(const short8*)&xr[(16 * g + m) * SDR + quad * 4];
      short8 a1 = {};
      if (quad < 2) a1 = *(const short8*)&xr[(16 * g + m) * SDR + 16 + quad * 4];
      f32x4 vg = {};
      vg = __builtin_amdgcn_mfma_f32_16x16x32_bf16(a0, wv0, vg, 0, 0, 0);
      vg = __builtin_amdgcn_mfma_f32_16x16x32_bf16(a1, wv1, vg, 0, 0, 0);
      // D: col=m (=p, valid m<8), row = 4*quad + r
      if (m < 8) {
        __hip_bfloat16* vr = v + (rowt + 16 * g + 4 * quad) * 8 + m;
#pragma unroll
        for (int r = 0; r < 4; ++r) vr[r * 8] = __float2bfloat16(vg[r]);
      }
    }
  }

  // ---- cross-wave reduce through LDS, then 2304 atomics per block ----
  __syncthreads();
  float* red = (float*)sh;
  if (wave >= 2) {
    float* dst = red + (wave - 2) * 2304 + lane * 36;
#pragma unroll
    for (int i = 0; i < 3; ++i)
#pragma unroll
      for (int j = 0; j < 3; ++j)
#pragma unroll
        for (int r = 0; r < 4; ++r) dst[(i * 3 + j) * 4 + r] = acc[i][j][r];
  }
  __syncthreads();
  if (wave < 2) {
    const float* s2 = red + wave * 2304 + lane * 36;
#pragma unroll
    for (int i = 0; i < 3; ++i)
#pragma unroll
      for (int j = 0; j < 3; ++j)
#pragma unroll
        for (int r = 0; r < 4; ++r) acc[i][j][r] += s2[(i * 3 + j) * 4 + r];
  }
  __syncthreads();
  if (wave == 1) {
    float* dst = red + lane * 36;
#pragma unroll
    for (int i = 0; i < 3; ++i)
#pragma unroll
      for (int j = 0; j < 3; ++j)
#pragma unroll
        for (int r = 0; r < 4; ++r) dst[(i * 3 + j) * 4 + r] = acc[i][j][r];
  }
  __syncthreads();
  if (wave == 0) {
    const float* s1 = red + lane * 36;
#pragma unroll
    for (int i = 0; i < 3; ++i)
#pragma unroll
      for (int j = 0; j < 3; ++j)
#pragma unroll
        for (int r = 0; r < 4; ++r) {
          float val = acc[i][j][r] + s1[(i * 3 + j) * 4 + r];
          atomicAdd(&G[(16 * i + quad * 4 + r) * 48 + 16 * j + m], val);
        }
  }
}

// ---------------- K2: epilogue -> Mt2[48 cols][8 k] bf16 fragment table ----
// W2[p][j] = sum_q attn[p][q] Wo[j][q];  Mt2[j*8+p] = bf16(W2[p][j])
__global__ void k_combine(const float* __restrict__ G,
                          const float* __restrict__ Wk,
                          const float* __restrict__ Wq,
                          const float* __restrict__ Wo,
                          __hip_bfloat16* __restrict__ Mt2) {
  __shared__ float sG[2304];
  __shared__ float sWk[384], sWq[384], sWo[384];
  __shared__ float sU[384];  // U[q][i] = sum_j G[i][j] Wk[q][j] -> q*48+i
  __shared__ float sA[64];   // softmax(S)
  const int t = threadIdx.x;  // 256

  for (int i = t; i < 2304; i += 256) sG[i] = G[i];
  for (int i = t; i < 384; i += 256) {
    sWk[i] = Wk[i]; sWq[i] = Wq[i]; sWo[i] = Wo[i];
  }
  __syncthreads();

  for (int e = t; e < 384; e += 256) {
    int q = e & 7, i = e >> 3;
    float s = 0.f;
#pragma unroll
    for (int j = 0; j < 48; ++j) s += sG[i * 48 + j] * sWk[q * 48 + j];
    sU[q * 48 + i] = s;
  }
  __syncthreads();

  if (t < 64) {  // wave 0: S[p][q] + row softmax over q
    int p = t >> 3;
    float s = 0.f;
#pragma unroll
    for (int i = 0; i < 48; ++i) s += sWq[p * 48 + i] * sU[(t & 7) * 48 + i];
    s *= 0.35355339059327373f;
    float mx = s;
    for (int d = 1; d < 8; d <<= 1) mx = fmaxf(mx, __shfl_xor(mx, d));
    float e = expf(s - mx);
    float den = e;
    for (int d = 1; d < 8; d <<= 1) den += __shfl_xor(den, d);
    sA[t] = e / den;
  }
  __syncthreads();

  // Mt2[col*8+p] = bf16( sum_q sA[p*8+q] * Wo[col*8+q] )
  for (int e = t; e < 384; e += 256) {
    int p = e & 7, col = e >> 3;
    float s = 0.f;
#pragma unroll
    for (int q = 0; q < 8; ++q) s += sA[p * 8 + q] * sWo[col * 8 + q];
    Mt2[col * 8 + p] = __float2bfloat16(s);
  }
}

// ---------------- K3: out = v @ W2 (bf16 MFMA, K=8 padded to 32) ----------------
// LDS-free. A-frag: quad 0 lanes hold a full v row (8 bf16 = one dwordx4 load);
// quads 1-3 are the k>=8 zero pad. B-frags from Mt2 (L2-resident).
__global__ __launch_bounds__(256) void k_out_v(const __hip_bfloat16* __restrict__ v,
                                               const __hip_bfloat16* __restrict__ Mt2,
                                               float* __restrict__ out, int N) {
  const int tid = threadIdx.x;
  const int wave = tid >> 6, lane = tid & 63;
  const int quad = lane >> 4, m = lane & 15;

  short8 b[3] = {short8{}, short8{}, short8{}};
  if (quad == 0) {
#pragma unroll
    for (int t = 0; t < 3; ++t)
      b[t] = *(const short8*)(Mt2 + (16 * t + m) * 8);
  }

  const int rows_per_block = N / GB2;             // 512
  const int rows_per_wave = rows_per_block >> 2;  // 128
  const int ng = rows_per_wave >> 4;              // 8 groups of 16 rows
  const long long base = (long long)blockIdx.x * rows_per_block + wave * rows_per_wave;

  for (int g = 0; g < ng; ++g) {
    const long long rowg = base + (long long)g * 16;
    short8 af = {};
    if (quad == 0) af = *(const short8*)(v + (rowg + m) * 8);
    f32x4 acc[3] = {};
#pragma unroll
    for (int t = 0; t < 3; ++t)
      acc[t] = __builtin_amdgcn_mfma_f32_16x16x32_bf16(af, b[t], acc[t], 0, 0, 0);
    float* orow = out + rowg * DI;
#pragma unroll
    for (int t = 0; t < 3; ++t)
#pragma unroll
      for (int r = 0; r < 4; ++r)
        orow[(quad * 4 + r) * DI + 16 * t + m] = acc[t][r];
  }
}

extern "C" void kernel_launch(void* const* d_in, const int* in_sizes, int n_in,
                              void* d_out, int out_size, void* d_ws, size_t ws_size,
                              hipStream_t stream) {
  const float* x  = (const float*)d_in[0];
  const float* Wk = (const float*)d_in[1];
  const float* Wq = (const float*)d_in[2];
  const float* Wv = (const float*)d_in[3];
  const float* Wo = (const float*)d_in[4];
  float* out = (float*)d_out;
  const int N = in_sizes[0] / DI;  // 1048576

  float* G = (float*)d_ws;                                       // 9216 B
  __hip_bfloat16* Mt2 = (__hip_bfloat16*)((char*)d_ws + 9216);   // 768 B
  __hip_bfloat16* v   = (__hip_bfloat16*)((char*)d_ws + 16384);  // N*16 B = 16.8 MB

  hipMemsetAsync(G, 0, 2304 * sizeof(float), stream);
  k_gram_v<<<GB1, 256, 0, stream>>>(x, Wv, G, v, N);
  k_combine<<<1, 256, 0, stream>>>(G, Wk, Wq, Wo, Mt2);
  k_out_v<<<GB2, 256, 0, stream>>>(v, Mt2, out, N);
}